// Round 4
// baseline (49.386 us; speedup 1.0000x reference)
//
#include <hip/hip_runtime.h>
#include <float.h>

#define GDIM 12
#define NC   144          // GDIM*GDIM
#define FINF 1.0e9f

// Padded 14x14 neighbor offsets in exact reference DIRS order.
__device__ __constant__ int POFF[8] = {-15, -14, -13, -1, 1, 13, 14, 15};

// Plain rotates within 16-lane DPP rows (rotation => no invalid lanes).
// Idle lanes 12..15 hold FINF, so the wrap-around value IS the boundary.
// We always combine both directions with min, so which one is "left" is
// irrelevant for correctness.
__device__ inline float rotA(float x) {
    return __int_as_float(__builtin_amdgcn_update_dpp(
        __float_as_int(x), __float_as_int(x), 0x121, 0xf, 0xf, false));
}
__device__ inline float rotB(float x) {
    return __int_as_float(__builtin_amdgcn_update_dpp(
        __float_as_int(x), __float_as_int(x), 0x12F, 0xf, 0xf, false));
}

// Full row relaxation (fast-sweeping step) for compile-time row i:
//   base = min(d_i, c_i + min(vertical/diagonal nbrs))       [exact: min dists over +]
//   then bidirectional SERIAL min-plus scan along the row:
//   f(j) = min(f(j), f(j-/+1) + c(j))  -- 11 steps each way.
// Serial scan keeps the reference's left-associated f32 path sums exactly,
// so the monotone fixed point is bit-identical to the reference's.
#define ROWFS(i) {                                                        \
    float uu = fminf(((i) > 0)        ? d[(i) > 0 ? (i)-1 : 0]   : FINF,  \
                     ((i) < GDIM - 1) ? d[(i) < GDIM-1 ? (i)+1 : GDIM-1] : FINF); \
    float nbrV = fminf(fminf(rotA(uu), rotB(uu)), uu);                    \
    float base = fminf(d[(i)], c[(i)] + nbrV);                            \
    float fF = base, fB = base;                                           \
    _Pragma("unroll")                                                     \
    for (int sc = 0; sc < GDIM - 1; ++sc) {                               \
        fF = fminf(fF, rotA(fF) + c[(i)]);                                \
        fB = fminf(fB, rotB(fB) + c[(i)]);                                \
    }                                                                     \
    float r = fminf(fF, fB);                                              \
    changed = changed | (r < d[(i)]);                                     \
    d[(i)] = r; }

__global__ __launch_bounds__(64)
void path_kernel(const int* __restrict__ w,
                 const float* __restrict__ costs,
                 int* __restrict__ out) {
    const int l = threadIdx.x;      // lane 0..63
    const int g = l >> 4;           // problem group 0..3 within the wave
    const int j = l & 15;           // column (0..11 active, 12..15 idle=INF)
    const int pbase = blockIdx.x * 4;

    __shared__ int4  s_w4[NC];      // 4 problems' weights (576 ints)
    __shared__ float dl[4][196];    // 14x14 padded dist, border = INF
    __shared__ int4  ml4[NC];       // 4 problems' masks (576 ints)
    int* s_w = (int*)s_w4;
    int* ml  = (int*)ml4;

    // int4 coalesced staging of weights + mask zeroing (144 int4 each)
    const int4* wv = (const int4*)(w + (size_t)pbase * NC);
    const int4 zero4 = make_int4(0, 0, 0, 0);
    s_w4[l] = wv[l];            ml4[l] = zero4;
    s_w4[64 + l] = wv[64 + l];  ml4[64 + l] = zero4;
    if (l < 16) { s_w4[128 + l] = wv[128 + l]; ml4[128 + l] = zero4; }
    {
        float* dlf = &dl[0][0];
        #pragma unroll
        for (int t = 0; t < 13; ++t) { int idx = t * 64 + l; if (idx < 784) dlf[idx] = FINF; }
    }
    __syncthreads();

    // per-lane column state: d[i] = dist(i, j), c[i] = cost(i, j)
    const bool act = (j < GDIM);
    float c[GDIM], d[GDIM];
    #pragma unroll
    for (int i = 0; i < GDIM; ++i) {
        c[i] = act ? costs[s_w[g * NC + i * GDIM + j]] : FINF;
        d[i] = FINF;
    }
    if (j == 0) d[0] = c[0];        // source cell (0,0)

    // Fast-sweeping: alternating down/up GS sweeps with full horizontal
    // relaxation per row. Converges in ~(#vertical path reversals + 2)
    // sweeps. Stop after TWO consecutive clean sweeps (down-clean alone
    // doesn't prove up-fixed). Monotone => exact f32 fixed point.
    int clean = 0;
    for (int s = 0; s < 64 && clean < 2; ++s) {
        bool changed = false;
        if ((s & 1) == 0) {
            #pragma unroll
            for (int i = 0; i < GDIM; ++i) ROWFS(i)
        } else {
            #pragma unroll
            for (int ii = 0; ii < GDIM; ++ii) { const int i = GDIM - 1 - ii; ROWFS(i) }
        }
        clean = (__ballot(changed) == 0ull) ? (clean + 1) : 0;
    }

    // dump dist into padded LDS interior
    if (act) {
        #pragma unroll
        for (int i = 0; i < GDIM; ++i) dl[g][(i + 1) * 14 + (j + 1)] = d[i];
    }
    __syncthreads();

    // backtrack: 4 walkers (lanes 0/16/32/48) in parallel. INF border makes
    // every neighbor read in-bounds; first-wins strict-< scan in DIRS order
    // == reference argmin over (valid ? dist : INF).
    if (j == 0) {
        int a = 12 * 14 + 12;                 // padded addr of (11,11)
        ml[g * NC + NC - 1] = 1;
        int guard = 0;
        while (a != (1 * 14 + 1) && guard < 200) {
            ++guard;
            float best = FLT_MAX; int ba = a;
            #pragma unroll
            for (int dd = 0; dd < 8; ++dd) {
                int na = a + POFF[dd];
                float v = dl[g][na];
                if (v < best) { best = v; ba = na; }   // first-wins tie
            }
            a = ba;
            int ii = a / 14 - 1, jj = a % 14 - 1;
            ml[g * NC + ii * GDIM + jj] = 1;
        }
    }
    __syncthreads();

    // int4 coalesced store (writes every output element; no stale state)
    int4* ov = (int4*)(out + (size_t)pbase * NC);
    ov[l] = ml4[l];
    ov[64 + l] = ml4[64 + l];
    if (l < 16) ov[128 + l] = ml4[128 + l];
}

extern "C" void kernel_launch(void* const* d_in, const int* in_sizes, int n_in,
                              void* d_out, int out_size, void* d_ws, size_t ws_size,
                              hipStream_t stream) {
    const int*   w     = (const int*)d_in[0];
    const float* costs = (const float*)d_in[1];
    int*         out   = (int*)d_out;
    const int K = in_sizes[0] / NC;          // 8192 problems
    path_kernel<<<dim3(K / 4), dim3(64), 0, stream>>>(w, costs, out);
}

// Round 5
// 28.547 us; speedup vs baseline: 1.7300x; 1.7300x over previous
//
#include <hip/hip_runtime.h>
#include <float.h>

#define GDIM 12
#define NC   144          // GDIM*GDIM
#define FINF 1.0e9f
#define KH   3            // horizontal hops per row visit

// Padded 14x14 neighbor offsets in exact reference DIRS order.
__device__ __constant__ int POFF[8] = {-15, -14, -13, -1, 1, 13, 14, 15};

// Rotates within 16-lane DPP rows. Idle lanes 12..15 hold FINF, so the
// wrap-around value IS the out-of-bounds guard; every use combines both
// directions with min, so the rotation convention is irrelevant.
__device__ inline float rotA(float x) {
    return __int_as_float(__builtin_amdgcn_update_dpp(
        __float_as_int(x), __float_as_int(x), 0x121, 0xf, 0xf, false));
}
__device__ inline float rotB(float x) {
    return __int_as_float(__builtin_amdgcn_update_dpp(
        __float_as_int(x), __float_as_int(x), 0x12F, 0xf, 0xf, false));
}

// Row visit for compile-time row i:
//   base = min(d_i, c_i + min(vert/diag nbrs)), then KH serial min-plus
//   hops along the row in both directions (left-folded f32 path sums ->
//   monotone relaxation with the reference's exact fixed point).
#define ROWK(i) {                                                         \
    float uu;                                                             \
    if ((i) == 0)              uu = d[1];                                 \
    else if ((i) == GDIM - 1)  uu = d[GDIM - 2];                          \
    else                       uu = fminf(d[(i)>0?(i)-1:0], d[(i)<GDIM-1?(i)+1:GDIM-1]); \
    float nbrV = fminf(fminf(rotA(uu), rotB(uu)), uu);                    \
    float fA = fminf(d[(i)], c[(i)] + nbrV);                              \
    float fB = fA;                                                        \
    _Pragma("unroll")                                                     \
    for (int sc = 0; sc < KH; ++sc) {                                     \
        fA = fminf(fA, rotA(fA) + c[(i)]);                                \
        fB = fminf(fB, rotB(fB) + c[(i)]);                                \
    }                                                                     \
    float r = fminf(fA, fB);                                              \
    changed = changed | (r < d[(i)]);                                     \
    d[(i)] = r; }

__global__ __launch_bounds__(64)
void path_kernel(const int* __restrict__ w,
                 const float* __restrict__ costs,
                 int* __restrict__ out) {
    const int l = threadIdx.x;      // lane 0..63
    const int g = l >> 4;           // problem group 0..3 within the wave
    const int j = l & 15;           // column (0..11 active, 12..15 idle=INF)
    const int pbase = blockIdx.x * 4;

    __shared__ int4  s_w4[NC];      // 4 problems' weights (576 ints)
    __shared__ float dl[4][196];    // 14x14 padded dist, border = INF
    __shared__ int4  ml4[NC];       // 4 problems' masks (576 ints)
    int* s_w = (int*)s_w4;
    int* ml  = (int*)ml4;

    // uniform scalar loads of the 5-entry cost table (s_load, broadcast)
    const float cv0 = costs[0], cv1 = costs[1], cv2 = costs[2],
                cv3 = costs[3], cv4 = costs[4];

    // int4 coalesced staging of weights + mask zeroing
    const int4* wv = (const int4*)(w + (size_t)pbase * NC);
    const int4 zero4 = make_int4(0, 0, 0, 0);
    s_w4[l] = wv[l];            ml4[l] = zero4;
    s_w4[64 + l] = wv[64 + l];  ml4[64 + l] = zero4;
    if (l < 16) { s_w4[128 + l] = wv[128 + l]; ml4[128 + l] = zero4; }
    {
        float* dlf = &dl[0][0];
        #pragma unroll
        for (int t = 0; t < 13; ++t) { int idx = t * 64 + l; if (idx < 784) dlf[idx] = FINF; }
    }
    __syncthreads();

    // per-lane column state via 4-cndmask table lookup (no global gather)
    const bool act = (j < GDIM);
    float c[GDIM], d[GDIM];
    #pragma unroll
    for (int i = 0; i < GDIM; ++i) {
        int wi = s_w[g * NC + i * GDIM + (act ? j : 0)];
        float cc = cv4;
        cc = (wi == 0) ? cv0 : cc;
        cc = (wi == 1) ? cv1 : cc;
        cc = (wi == 2) ? cv2 : cc;
        cc = (wi == 3) ? cv3 : cc;
        c[i] = act ? cc : FINF;
        d[i] = FINF;
    }
    if (j == 0) d[0] = c[0];        // source cell (0,0)

    // Alternating down/up GS sweeps with KH-hop horizontal relaxation per
    // row visit. Stop after TWO consecutive clean sweeps. Monotone chaotic
    // relaxation from INF -> reference's exact f32 fixed point.
    int clean = 0;
    for (int s = 0; s < 64 && clean < 2; ++s) {
        bool changed = false;
        if ((s & 1) == 0) {
            #pragma unroll
            for (int i = 0; i < GDIM; ++i) ROWK(i)
        } else {
            #pragma unroll
            for (int ii = 0; ii < GDIM; ++ii) { const int i = GDIM - 1 - ii; ROWK(i) }
        }
        clean = (__ballot(changed) == 0ull) ? (clean + 1) : 0;
    }

    // dump dist into padded LDS interior
    if (act) {
        #pragma unroll
        for (int i = 0; i < GDIM; ++i) dl[g][(i + 1) * 14 + (j + 1)] = d[i];
    }
    __syncthreads();

    // backtrack: 4 walkers (lanes 0/16/32/48) in parallel. INF border keeps
    // all reads in-bounds; first-wins strict-< scan in DIRS order ==
    // reference argmin over (valid ? dist : INF).
    if (j == 0) {
        int a = 12 * 14 + 12;                 // padded addr of (11,11)
        ml[g * NC + NC - 1] = 1;
        int guard = 0;
        while (a != (1 * 14 + 1) && guard < 200) {
            ++guard;
            float best = FLT_MAX; int ba = a;
            #pragma unroll
            for (int dd = 0; dd < 8; ++dd) {
                int na = a + POFF[dd];
                float v = dl[g][na];
                if (v < best) { best = v; ba = na; }   // first-wins tie
            }
            a = ba;
            int ii = a / 14 - 1, jj = a % 14 - 1;
            ml[g * NC + ii * GDIM + jj] = 1;
        }
    }
    __syncthreads();

    // int4 coalesced store (writes every output element; no stale state)
    int4* ov = (int4*)(out + (size_t)pbase * NC);
    ov[l] = ml4[l];
    ov[64 + l] = ml4[64 + l];
    if (l < 16) ov[128 + l] = ml4[128 + l];
}

extern "C" void kernel_launch(void* const* d_in, const int* in_sizes, int n_in,
                              void* d_out, int out_size, void* d_ws, size_t ws_size,
                              hipStream_t stream) {
    const int*   w     = (const int*)d_in[0];
    const float* costs = (const float*)d_in[1];
    int*         out   = (int*)d_out;
    const int K = in_sizes[0] / NC;          // 8192 problems
    path_kernel<<<dim3(K / 4), dim3(64), 0, stream>>>(w, costs, out);
}

// Round 6
// 25.844 us; speedup vs baseline: 1.9109x; 1.1046x over previous
//
#include <hip/hip_runtime.h>
#include <float.h>

#define GDIM 12
#define NC   144          // GDIM*GDIM
#define FINF 1.0e9f

// Padded 14x14 neighbor offsets in exact reference DIRS order.
__device__ __constant__ int POFF[8] = {-15, -14, -13, -1, 1, 13, 14, 15};

// Rotate within 16-lane DPP rows (0x120 | n = row_ror:n). Idle lanes 12..15
// hold FINF => wrap-around IS the out-of-bounds guard; neighbor uses combine
// both directions with min, so rotation convention is irrelevant.
template<int CTRL>
__device__ inline float rot(float x) {
    return __int_as_float(__builtin_amdgcn_update_dpp(
        __float_as_int(x), __float_as_int(x), CTRL, 0xf, 0xf, false));
}

// Row relaxation (compile-time i), tracking the min value of any change
// (chmin) for the rising-frontier termination test.
#define ROWU(i) {                                                          \
    float dm1 = ((i) > 0)        ? d[(i) > 0 ? (i)-1 : 0]        : FINF;   \
    float dp1 = ((i) < GDIM - 1) ? d[(i) < GDIM-1 ? (i)+1 : GDIM-1] : FINF;\
    float V   = fminf(dm1, dp1);                                           \
    float cm3 = fminf(V, d[(i)]);                                          \
    float nbr = fminf(fminf(rot<0x121>(cm3), rot<0x12F>(cm3)), V);         \
    float nd  = c[(i)] + nbr;                                              \
    float dn  = fminf(d[(i)], nd);                                         \
    chmin = (dn < d[(i)]) ? fminf(chmin, dn) : chmin;                      \
    d[(i)] = dn; }

// Red-black sweep: even rows then odd rows -> 6 independent chains of ILP.
#define RB_SWEEP {                                                         \
    _Pragma("unroll")                                                      \
    for (int i = 0; i < GDIM; i += 2) ROWU(i)                              \
    _Pragma("unroll")                                                      \
    for (int i = 1; i < GDIM; i += 2) ROWU(i)                              \
}

// 16-lane group min-reduction via rotate-min (all lanes get the result).
#define GRPMIN(x) {                                                        \
    x = fminf(x, rot<0x121>(x));                                           \
    x = fminf(x, rot<0x122>(x));                                           \
    x = fminf(x, rot<0x124>(x));                                           \
    x = fminf(x, rot<0x128>(x)); }

__global__ __launch_bounds__(64)
void path_kernel(const int* __restrict__ w,
                 const float* __restrict__ costs,
                 int* __restrict__ out) {
    const int l = threadIdx.x;      // lane 0..63
    const int g = l >> 4;           // problem group 0..3 within the wave
    const int j = l & 15;           // column (0..11 active, 12..15 idle=INF)
    const int pbase = blockIdx.x * 4;

    __shared__ int4  s_w4[NC];      // 4 problems' weights (576 ints)
    __shared__ float dl[4][196];    // 14x14 padded dist, border = INF
    __shared__ int4  ml4[NC];       // 4 problems' masks (576 ints)
    int* s_w = (int*)s_w4;
    int* ml  = (int*)ml4;

    // uniform scalar loads of the 5-entry cost table (broadcast)
    const float cv0 = costs[0], cv1 = costs[1], cv2 = costs[2],
                cv3 = costs[3], cv4 = costs[4];

    // int4 coalesced staging of weights + mask zeroing
    const int4* wv = (const int4*)(w + (size_t)pbase * NC);
    const int4 zero4 = make_int4(0, 0, 0, 0);
    s_w4[l] = wv[l];            ml4[l] = zero4;
    s_w4[64 + l] = wv[64 + l];  ml4[64 + l] = zero4;
    if (l < 16) { s_w4[128 + l] = wv[128 + l]; ml4[128 + l] = zero4; }
    {
        float* dlf = &dl[0][0];
        #pragma unroll
        for (int t = 0; t < 13; ++t) { int idx = t * 64 + l; if (idx < 784) dlf[idx] = FINF; }
    }
    __syncthreads();

    // per-lane column state via 4-cndmask table lookup (no global gather)
    const bool act = (j < GDIM);
    float c[GDIM], d[GDIM];
    #pragma unroll
    for (int i = 0; i < GDIM; ++i) {
        int wi = s_w[g * NC + i * GDIM + (act ? j : 0)];
        float cc = cv4;
        cc = (wi == 0) ? cv0 : cc;
        cc = (wi == 1) ? cv1 : cc;
        cc = (wi == 2) ? cv2 : cc;
        cc = (wi == 3) ? cv3 : cc;
        c[i] = act ? cc : FINF;
        d[i] = FINF;
    }
    if (j == 0) d[0] = c[0];        // source cell (0,0)

    // RB relaxation with rising-frontier early stop.
    // Soundness: updates only decrease; if every change in a sweep has
    // value >= X then every later change has value >= X + min_cost
    // (induction over update order). Once min(changed values over a full
    // 2-sweep pair) > d(11,11), all cells with value <= d(11,11) are final
    // and still-changing cells' finals stay above every value the backtrack
    // argmin selects -> traced mask == reference mask. chmin==FINF (no
    // change in pair) => fixed point. Cap 80 pairs = 160 sweeps >= the
    // reference's 144-sweep guarantee (GS dominates Jacobi pointwise).
    bool done = false;
    for (int pair = 0; pair < 80 && __ballot(!done) != 0ull; ++pair) {
        float chmin = FINF;
        RB_SWEEP
        RB_SWEEP
        float cm = chmin;
        GRPMIN(cm)
        float dv = (act && j == GDIM - 1) ? d[GDIM - 1] : FINF;
        GRPMIN(dv)
        done = done || (cm > dv) || (cm >= FINF);
    }

    // dump dist into padded LDS interior
    if (act) {
        #pragma unroll
        for (int i = 0; i < GDIM; ++i) dl[g][(i + 1) * 14 + (j + 1)] = d[i];
    }
    __syncthreads();

    // backtrack: 4 walkers (lanes 0/16/32/48) in parallel. INF border keeps
    // all reads in-bounds; first-wins strict-< scan in DIRS order ==
    // reference argmin over (valid ? dist : INF).
    if (j == 0) {
        int a = 12 * 14 + 12;                 // padded addr of (11,11)
        ml[g * NC + NC - 1] = 1;
        int guard = 0;
        while (a != (1 * 14 + 1) && guard < 200) {
            ++guard;
            float best = FLT_MAX; int ba = a;
            #pragma unroll
            for (int dd = 0; dd < 8; ++dd) {
                int na = a + POFF[dd];
                float v = dl[g][na];
                if (v < best) { best = v; ba = na; }   // first-wins tie
            }
            a = ba;
            int ii = a / 14 - 1, jj = a % 14 - 1;
            ml[g * NC + ii * GDIM + jj] = 1;
        }
    }
    __syncthreads();

    // int4 coalesced store (writes every output element; no stale state)
    int4* ov = (int4*)(out + (size_t)pbase * NC);
    ov[l] = ml4[l];
    ov[64 + l] = ml4[64 + l];
    if (l < 16) ov[128 + l] = ml4[128 + l];
}

extern "C" void kernel_launch(void* const* d_in, const int* in_sizes, int n_in,
                              void* d_out, int out_size, void* d_ws, size_t ws_size,
                              hipStream_t stream) {
    const int*   w     = (const int*)d_in[0];
    const float* costs = (const float*)d_in[1];
    int*         out   = (int*)d_out;
    const int K = in_sizes[0] / NC;          // 8192 problems
    path_kernel<<<dim3(K / 4), dim3(64), 0, stream>>>(w, costs, out);
}

// Round 7
// 24.961 us; speedup vs baseline: 1.9786x; 1.0354x over previous
//
#include <hip/hip_runtime.h>
#include <float.h>

#define GDIM 12
#define NC   144          // GDIM*GDIM
#define FINF 1.0e9f

// Padded 14x14 neighbor offsets in exact reference DIRS order.
__device__ __constant__ int POFF[8] = {-15, -14, -13, -1, 1, 13, 14, 15};

// Rotate within 16-lane DPP rows. Idle lanes 12..15 hold FINF => wrap-around
// IS the out-of-bounds guard; both directions are min'd, so convention is
// irrelevant.
template<int CTRL>
__device__ inline float rot(float x) {
    return __int_as_float(__builtin_amdgcn_update_dpp(
        __float_as_int(x), __float_as_int(x), CTRL, 0xf, 0xf, false));
}

// Sequential GS row update: instant propagation along the register axis.
// Exact reference expression: D[i] = min(D[i], C[i] + min(8 neighbors)).
#define ROWU(i, C, D) {                                                    \
    float dm1 = ((i) > 0)        ? D[(i) > 0 ? (i)-1 : 0]        : FINF;   \
    float dp1 = ((i) < GDIM - 1) ? D[(i) < GDIM-1 ? (i)+1 : GDIM-1] : FINF;\
    float V   = fminf(dm1, dp1);                                           \
    float cm3 = fminf(V, D[(i)]);                                          \
    float nbr = fminf(fminf(rot<0x121>(cm3), rot<0x12F>(cm3)), V);         \
    D[(i)] = fminf(D[(i)], C[(i)] + nbr); }

#define SWEEP_DN(C, D) { _Pragma("unroll")                                 \
    for (int i = 0; i < GDIM; ++i) ROWU(i, C, D) }
#define SWEEP_UP(C, D) { _Pragma("unroll")                                 \
    for (int q = 0; q < GDIM; ++q) { const int i = GDIM - 1 - q; ROWU(i, C, D) } }

__global__ __launch_bounds__(64)
void path_kernel(const int* __restrict__ w,
                 const float* __restrict__ costs,
                 int* __restrict__ out) {
    const int l = threadIdx.x;      // lane 0..63
    const int g = l >> 4;           // problem group 0..3 within the wave
    const int j = l & 15;           // column (0..11 active, 12..15 idle=INF)
    const int pbase = blockIdx.x * 4;

    __shared__ int4  s_w4[NC];      // 4 problems' weights (576 ints)
    __shared__ float dl[4][200];    // 14x14 padded dist (196) + slack
    __shared__ int4  ml4[NC];       // 4 problems' masks (576 ints)
    int* s_w = (int*)s_w4;
    int* ml  = (int*)ml4;

    // uniform scalar loads of the 5-entry cost table (broadcast)
    const float cv0 = costs[0], cv1 = costs[1], cv2 = costs[2],
                cv3 = costs[3], cv4 = costs[4];

    // int4 coalesced staging of weights + mask zeroing + INF-fill dl
    const int4* wv = (const int4*)(w + (size_t)pbase * NC);
    const int4 zero4 = make_int4(0, 0, 0, 0);
    s_w4[l] = wv[l];            ml4[l] = zero4;
    s_w4[64 + l] = wv[64 + l];  ml4[64 + l] = zero4;
    if (l < 16) { s_w4[128 + l] = wv[128 + l]; ml4[128 + l] = zero4; }
    {
        float* dlf = &dl[0][0];
        #pragma unroll
        for (int t = 0; t < 13; ++t) { int idx = t * 64 + l; if (idx < 800) dlf[idx] = FINF; }
    }
    __syncthreads();

    const bool act = (j < GDIM);
    float* A = &dl[g][0];

    // c  = normal layout: lane j owns column j, reg i = row i  -> cell (i,j)
    // ct = transposed   : lane j owns row    j, reg i = col i  -> cell (j,i)
    float c[GDIM], ct[GDIM], d[GDIM];
    #pragma unroll
    for (int i = 0; i < GDIM; ++i) {
        int wiN = s_w[g * NC + i * GDIM + (act ? j : 0)];
        int idxT = act ? (g * NC + j * GDIM + i) : 0;
        int wiT = s_w[idxT];
        float cN = cv4, cT = cv4;
        cN = (wiN == 0) ? cv0 : cN;  cT = (wiT == 0) ? cv0 : cT;
        cN = (wiN == 1) ? cv1 : cN;  cT = (wiT == 1) ? cv1 : cT;
        cN = (wiN == 2) ? cv2 : cN;  cT = (wiT == 2) ? cv2 : cT;
        cN = (wiN == 3) ? cv3 : cN;  cT = (wiT == 3) ? cv3 : cT;
        c[i]  = act ? cN : FINF;
        ct[i] = act ? cT : FINF;
        d[i] = FINF;
    }
    if (j == 0) d[0] = c[0];        // source cell (0,0)

    // Cycle: {down, up} in normal layout (vertical-monotone segments instant),
    // transpose, {down, up} in transposed layout (= right/left sweeps,
    // horizontal-monotone segments instant), transpose back, convergence
    // check by snapshot compare (monotone decrease => any d<dp <=> changed;
    // clean full cycle <=> fixed point). Cap 40 cycles = 160 sweeps >= the
    // reference's 144-sweep Jacobi guarantee (GS dominates Jacobi pointwise).
    for (int cyc = 0; cyc < 40; ++cyc) {
        float dp[GDIM];
        #pragma unroll
        for (int i = 0; i < GDIM; ++i) dp[i] = d[i];

        SWEEP_DN(c, d)
        SWEEP_UP(c, d)

        // T1: normal -> transposed (guarded: idle lanes stay FINF, border
        // stays INF). Within-wave LDS ordering handled by compiler waitcnts.
        if (act) {
            #pragma unroll
            for (int i = 0; i < GDIM; ++i) A[(i + 1) * 14 + (j + 1)] = d[i];
            #pragma unroll
            for (int i = 0; i < GDIM; ++i) d[i] = A[(j + 1) * 14 + (i + 1)];
        }

        SWEEP_DN(ct, d)
        SWEEP_UP(ct, d)

        // T2: transposed -> normal; leaves dl interior = current dist in
        // normal (row,col) layout for the backtrack.
        if (act) {
            #pragma unroll
            for (int i = 0; i < GDIM; ++i) A[(j + 1) * 14 + (i + 1)] = d[i];
            #pragma unroll
            for (int i = 0; i < GDIM; ++i) d[i] = A[(i + 1) * 14 + (j + 1)];
        }

        bool ch = false;
        #pragma unroll
        for (int i = 0; i < GDIM; ++i) ch = ch | (d[i] < dp[i]);
        if (__ballot(ch) == 0ull) break;
    }
    __syncthreads();

    // backtrack: 4 walkers (lanes 0/16/32/48) in parallel on dl (already
    // populated by T2). INF border keeps reads in-bounds; first-wins
    // strict-< scan in DIRS order == reference argmin over (valid?dist:INF).
    if (j == 0) {
        int a = 12 * 14 + 12;                 // padded addr of (11,11)
        ml[g * NC + NC - 1] = 1;
        int guard = 0;
        while (a != (1 * 14 + 1) && guard < 200) {
            ++guard;
            float best = FLT_MAX; int ba = a;
            #pragma unroll
            for (int dd = 0; dd < 8; ++dd) {
                int na = a + POFF[dd];
                float v = dl[g][na];
                if (v < best) { best = v; ba = na; }   // first-wins tie
            }
            a = ba;
            int ii = a / 14 - 1, jj = a % 14 - 1;
            ml[g * NC + ii * GDIM + jj] = 1;
        }
    }
    __syncthreads();

    // int4 coalesced store (writes every output element; no stale state)
    int4* ov = (int4*)(out + (size_t)pbase * NC);
    ov[l] = ml4[l];
    ov[64 + l] = ml4[64 + l];
    if (l < 16) ov[128 + l] = ml4[128 + l];
}

extern "C" void kernel_launch(void* const* d_in, const int* in_sizes, int n_in,
                              void* d_out, int out_size, void* d_ws, size_t ws_size,
                              hipStream_t stream) {
    const int*   w     = (const int*)d_in[0];
    const float* costs = (const float*)d_in[1];
    int*         out   = (int*)d_out;
    const int K = in_sizes[0] / NC;          // 8192 problems
    path_kernel<<<dim3(K / 4), dim3(64), 0, stream>>>(w, costs, out);
}